// Round 13
// baseline (170.942 us; speedup 1.0000x reference)
//
#include <hip/hip_runtime.h>
#include <cstdint>
#include <cstddef>
#include <math.h>

typedef short bf16x8 __attribute__((ext_vector_type(8)));
typedef float f32x4 __attribute__((ext_vector_type(4)));
typedef unsigned long long u64;

#define NEG_HUGE (-3.0e38f)

__device__ __forceinline__ ushort f2bf(float x) {
    union { float f; uint32_t u; } a; a.f = x;
    uint32_t r = a.u + 0x7FFF + ((a.u >> 16) & 1);   // RNE
    return (ushort)(r >> 16);
}

__device__ __forceinline__ void gload_lds16(const void* g, void* l) {
    __builtin_amdgcn_global_load_lds(
        (const __attribute__((address_space(1))) uint32_t*)g,
        (__attribute__((address_space(3))) uint32_t*)l, 16, 0, 0);
}

#define SCHED() __builtin_amdgcn_sched_barrier(0)
#define SBAR() do { SCHED(); __builtin_amdgcn_s_barrier(); SCHED(); } while (0)

// ---------------- weight prep ----------------
__global__ void prep_conv_T(const float* __restrict__ w, ushort* __restrict__ WT,
                            int Cin, int Cout, int Nrows, int Kpad) {
    int idx = blockIdx.x * 256 + threadIdx.x;
    if (idx >= Nrows * Kpad) return;
    int n = idx / Kpad, k = idx - n * Kpad;
    float val = 0.f;
    if (k < Cin * 3) {
        int co = n / 3, l = n % 3, ci = k / 3, lx = k % 3;
        int t = lx - l + 1;
        if (t >= 0 && t < 3) val = w[(co * Cin + ci) * 3 + t];
    }
    WT[idx] = f2bf(val);
}

__global__ void prep_lin_T(const float* __restrict__ wl, ushort* __restrict__ WT,
                           int K, int Nreal, int Npad) {
    int idx = blockIdx.x * 256 + threadIdx.x;
    if (idx >= Npad * K) return;
    int n = idx / K, k = idx - n * K;
    WT[idx] = (n < Nreal) ? f2bf(wl[n * K + k]) : (ushort)0;
}

// ---------------- conv1: fused convert + mask + GEMM ----------------
// grid (256 m-tiles, 2 n-halves). Block: 64 rows x 192 cols. LDS 72KB -> 2 blocks/CU.
// Per chunk c: stage_write(c); lgkm+BAR; loadW(c+1)[3]; loadS(c+3)[2]; vmcnt(7)
//   [drains exactly S(c+1)+W(c): S has 2 chunk-times of flight]; BAR; 12 MFMA/wave.
// S rotates 3 register buffers; W double-buffered LDS; both barriers required
// (cross-wave DMA visibility + W-buffer WAR protection).
__global__ __launch_bounds__(512, 4)
void conv1_kernel(const float* __restrict__ state, const ushort* __restrict__ W1T,
                  const float* __restrict__ b1, ushort* __restrict__ X1g,
                  uint32_t* __restrict__ maskg)
{
    extern __shared__ char lds[];
    char* BF0 = lds;                                // 64*128 = 8192
    char* BF1 = lds + 8192;
    char* Wb0 = lds + 16384;                        // 192*128 = 24576
    char* Wb1 = lds + 40960;
    uint32_t* maskw = (uint32_t*)(lds + 65536);     // [64][25] = 6400

    const int tid = threadIdx.x, lane = tid & 63, wid = tid >> 6;
    const int m0 = blockIdx.x * 64;
    const int n0 = blockIdx.y * 192;
    const bool domask = (blockIdx.y == 0);
    const int ml = lane & 15, kq = lane >> 4;
    const int mbase = (wid >> 2) * 32;              // 2 M-waves
    const int wn0 = (wid & 3) * 48;                 // 4 N-waves x 48 cols

    const int srow = tid >> 3, seg = tid & 7;       // 8 threads/row, 8 floats each
    const float* sbase = state + (size_t)(m0 + srow) * 2400 + seg * 8;

    f32x4 acc[3][2];
    #pragma unroll
    for (int f = 0; f < 3; ++f)
        #pragma unroll
        for (int mi = 0; mi < 2; ++mi) acc[f][mi] = (f32x4){0.f, 0.f, 0.f, 0.f};

    auto loadS = [&](float4 (&sv)[2], int c) {
        int kb = c * 64 + seg * 8;
        if (kb < 2400) {
            sv[0] = *(const float4*)(sbase + c * 64);
            sv[1] = *(const float4*)(sbase + c * 64 + 4);
        } else {
            sv[0] = (float4){0.f, 0.f, 0.f, 0.f};
            sv[1] = (float4){0.f, 0.f, 0.f, 0.f};
        }
    };
    auto stage_write = [&](float4 (&sv)[2], int c, char* dst) {
        float fv[8] = {sv[0].x, sv[0].y, sv[0].z, sv[0].w,
                       sv[1].x, sv[1].y, sv[1].z, sv[1].w};
        bf16x8 h;
        #pragma unroll
        for (int j = 0; j < 8; ++j) h[j] = (short)f2bf(fv[j]);
        *(bf16x8*)(dst + srow * 128 + ((seg * 16) ^ ((srow & 7) << 4))) = h;
        if (domask) {
            int kbase = c * 64 + seg * 8;
            int kmod = kbase % 3;
            uint32_t* mrow = &maskw[srow * 25];
            #define MCHK(J) { if (fv[J] != 0.0f) { int a = (kbase + (J)) / 3; \
                              atomicOr(&mrow[a >> 5], 1u << (a & 31)); } }
            if (kmod == 0)      { MCHK(2) MCHK(5) }
            else if (kmod == 1) { MCHK(1) MCHK(4) MCHK(7) }
            else                { MCHK(0) MCHK(3) MCHK(6) }
            #undef MCHK
        }
    };
    auto loadW = [&](int c, char* dst) {            // 24KB: 192 rows x 64 k
        #pragma unroll
        for (int i = 0; i < 3; ++i) {
            int s = i * 512 + tid;
            int r = s >> 3, o8 = s & 7;
            gload_lds16(W1T + (size_t)(n0 + r) * 2432 + c * 64 + ((o8 ^ (r & 7)) * 8),
                        dst + s * 16);
        }
    };
    auto mfmaC = [&](const char* wb, const char* sb) {
        #pragma unroll
        for (int ks = 0; ks < 2; ++ks) {
            bf16x8 af[3], bv[2];
            #pragma unroll
            for (int f = 0; f < 3; ++f) {
                int n = wn0 + f * 16 + ml;
                af[f] = *(const bf16x8*)(wb + n * 128 + (((ks * 4 + kq) * 16) ^ ((n & 7) << 4)));
            }
            #pragma unroll
            for (int mi = 0; mi < 2; ++mi) {
                int m = mbase + mi * 16 + ml;
                bv[mi] = *(const bf16x8*)(sb + m * 128 + (((ks * 4 + kq) * 16) ^ ((m & 7) << 4)));
            }
            #pragma unroll
            for (int f = 0; f < 3; ++f)
                #pragma unroll
                for (int mi = 0; mi < 2; ++mi)
                    acc[f][mi] = __builtin_amdgcn_mfma_f32_16x16x32_bf16(af[f], bv[mi], acc[f][mi], 0, 0, 0);
        }
    };

    // prologue: W(0) + S(0..2); drain through S(0) (leaves S1,S2 = 4 in flight)
    for (int i = tid; i < 64 * 25; i += 512) maskw[i] = 0;
    float4 sv0[2], sv1[2], sv2[2];
    loadW(0, Wb0);
    loadS(sv0, 0);
    loadS(sv1, 1);
    loadS(sv2, 2);
    SCHED();
    asm volatile("s_waitcnt vmcnt(4) lgkmcnt(0)" ::: "memory");
    SBAR();

    // BODY(c): steady-state vmcnt(7) drains exactly S(c+1)+W(c).
    #define BODY(SV, C, SB, WBC, WBN) do {                                   \
        stage_write(SV, (C), SB);                                            \
        SCHED();                                                             \
        asm volatile("s_waitcnt lgkmcnt(0)" ::: "memory");                   \
        SBAR();                                                              \
        loadW(((C) + 1 > 37) ? 37 : (C) + 1, WBN);                           \
        loadS(SV, ((C) + 3 > 37) ? 37 : (C) + 3);                            \
        SCHED();                                                             \
        asm volatile("s_waitcnt vmcnt(7)" ::: "memory");                     \
        SBAR();                                                              \
        mfmaC(WBC, SB);                                                      \
    } while (0)

    #pragma unroll 1
    for (int p = 0; p < 12; ++p) {
        int c = 3 * p;
        BODY(sv0, c,     (c & 1) ? BF1 : BF0, (c & 1) ? Wb1 : Wb0, (c & 1) ? Wb0 : Wb1);
        BODY(sv1, c + 1, ((c + 1) & 1) ? BF1 : BF0, ((c + 1) & 1) ? Wb1 : Wb0, ((c + 1) & 1) ? Wb0 : Wb1);
        BODY(sv2, c + 2, ((c + 2) & 1) ? BF1 : BF0, ((c + 2) & 1) ? Wb1 : Wb0, ((c + 2) & 1) ? Wb0 : Wb1);
    }
    BODY(sv0, 36, BF0, Wb0, Wb1);
    BODY(sv1, 37, BF1, Wb1, Wb0);
    #undef BODY

    asm volatile("s_waitcnt vmcnt(0) lgkmcnt(0)" ::: "memory");
    SBAR();

    // epilogue -> X1g [16384][384] bf16, cols n0..n0+191
    {
        const int nq4 = (lane >> 4) * 4;
        #pragma unroll
        for (int f = 0; f < 3; ++f) {
            int n4 = n0 + wn0 + f * 16 + nq4;
            float bv0 = b1[n4 / 3], bv1 = b1[(n4 + 1) / 3];
            float bv2 = b1[(n4 + 2) / 3], bv3 = b1[(n4 + 3) / 3];
            #pragma unroll
            for (int mi = 0; mi < 2; ++mi) {
                int m = mbase + mi * 16 + ml;
                ushort4 o;
                o.x = f2bf(fmaxf(acc[f][mi][0] + bv0, 0.f));
                o.y = f2bf(fmaxf(acc[f][mi][1] + bv1, 0.f));
                o.z = f2bf(fmaxf(acc[f][mi][2] + bv2, 0.f));
                o.w = f2bf(fmaxf(acc[f][mi][3] + bv3, 0.f));
                *(ushort4*)(X1g + (size_t)(m0 + m) * 384 + n4) = o;
            }
        }
    }

    // finalize mask: visited | user_any | chan_full (y==0 blocks, one thread/sample)
    if (domask && tid < 64) {
        uint32_t* mw = &maskw[tid * 25];
        const u64 M40 = (1ull << 40) - 1;
        u64 ua = 0; uint32_t cf = 0;
        #pragma unroll
        for (int g = 0; g < 5; ++g) {
            uint32_t w0 = mw[5*g], w1 = mw[5*g+1], w2 = mw[5*g+2], w3 = mw[5*g+3], w4 = mw[5*g+4];
            u64 c0 = ( (u64)w0        | ((u64)w1 << 32)) & M40;
            u64 c1 = (((u64)w1 >> 8)  | ((u64)w2 << 24)) & M40;
            u64 c2 = (((u64)w2 >> 16) | ((u64)w3 << 16)) & M40;
            u64 c3 = (((u64)w3 >> 24) | ((u64)w4 << 8))  & M40;
            ua |= c0 | c1 | c2 | c3;
            if (__popcll(c0) >= 2) cf |= 1u << (4*g);
            if (__popcll(c1) >= 2) cf |= 1u << (4*g+1);
            if (__popcll(c2) >= 2) cf |= 1u << (4*g+2);
            if (__popcll(c3) >= 2) cf |= 1u << (4*g+3);
        }
        uint32_t* mg = maskg + (size_t)(m0 + tid) * 25;
        #pragma unroll
        for (int g = 0; g < 5; ++g) {
            uint32_t w0 = mw[5*g], w1 = mw[5*g+1], w2 = mw[5*g+2], w3 = mw[5*g+3], w4 = mw[5*g+4];
            u64 c0 = ( (u64)w0        | ((u64)w1 << 32)) & M40;
            u64 c1 = (((u64)w1 >> 8)  | ((u64)w2 << 24)) & M40;
            u64 c2 = (((u64)w2 >> 16) | ((u64)w3 << 16)) & M40;
            u64 c3 = (((u64)w3 >> 24) | ((u64)w4 << 8))  & M40;
            u64 m0v = c0 | ua | (((cf >> (4*g))     & 1u) ? M40 : 0ull);
            u64 m1v = c1 | ua | (((cf >> (4*g + 1)) & 1u) ? M40 : 0ull);
            u64 m2v = c2 | ua | (((cf >> (4*g + 2)) & 1u) ? M40 : 0ull);
            u64 m3v = c3 | ua | (((cf >> (4*g + 3)) & 1u) ? M40 : 0ull);
            mg[5*g]   = (uint32_t)m0v;
            mg[5*g+1] = (uint32_t)(m0v >> 32) | (uint32_t)(m1v << 8);
            mg[5*g+2] = (uint32_t)(m1v >> 24) | (uint32_t)(m2v << 16);
            mg[5*g+3] = (uint32_t)(m2v >> 16) | (uint32_t)(m3v << 24);
            mg[5*g+4] = (uint32_t)(m3v >> 8);
        }
    }
}

// ---------------- uniform GEMM layer, depth-2 counted pipeline (unchanged) ----------------
template<int K, bool BDIV3, bool RELU, bool F32OUT>
__global__ __launch_bounds__(512, 4)
void glayer3(const ushort* __restrict__ Ag, const ushort* __restrict__ WTg,
             const float* __restrict__ bias, void* __restrict__ Yg, int ldy,
             const uint32_t* __restrict__ maskg)
{
    constexpr int MF = 4, NF = 3;
    constexpr int MT = 128, NT = 192;
    constexpr int NC = K / 64;
    constexpr int ABYTES = MT * 128;
    constexpr int WBYTES = NT * 128;
    static_assert(NC >= 3, "pipeline assumes >=3 chunks");
    extern __shared__ char lds[];

    const int tid = threadIdx.x, lane = tid & 63, wid = tid >> 6;
    const int m0 = blockIdx.x * MT;
    const int n0 = blockIdx.y * NT;
    const int ml = lane & 15, kq = lane >> 4;
    const int mw = wid >> 2, nw = wid & 3;
    const int mbase = mw * MF * 16;
    const int wn0 = nw * NF * 16;

    f32x4 acc[NF][MF];
    #pragma unroll
    for (int f = 0; f < NF; ++f)
        #pragma unroll
        for (int mi = 0; mi < MF; ++mi) acc[f][mi] = (f32x4){0.f, 0.f, 0.f, 0.f};

    auto stage = [&](int c, int b) {
        char* Ab = lds + b * ABYTES;
        char* Wb = lds + 2 * ABYTES + b * WBYTES;
        #pragma unroll
        for (int i = 0; i < 2; ++i) {
            int s = i * 512 + tid;
            int r = s >> 3, o8 = s & 7;
            gload_lds16(Ag + (size_t)(m0 + r) * K + c * 64 + ((o8 ^ (r & 7)) * 8),
                        Ab + s * 16);
        }
        #pragma unroll
        for (int i = 0; i < 3; ++i) {
            int s = i * 512 + tid;
            int r = s >> 3, o8 = s & 7;
            gload_lds16(WTg + (size_t)(n0 + r) * K + c * 64 + ((o8 ^ (r & 7)) * 8),
                        Wb + s * 16);
        }
    };
    auto mfmaC = [&](int b) {
        const char* Ab = lds + b * ABYTES;
        const char* Wb = lds + 2 * ABYTES + b * WBYTES;
        #pragma unroll
        for (int ks = 0; ks < 2; ++ks) {
            bf16x8 af[NF], bv[MF];
            #pragma unroll
            for (int f = 0; f < NF; ++f) {
                int n = wn0 + f * 16 + ml;
                af[f] = *(const bf16x8*)(Wb + n * 128 + (((ks * 4 + kq) * 16) ^ ((n & 7) << 4)));
            }
            #pragma unroll
            for (int mi = 0; mi < MF; ++mi) {
                int m = mbase + mi * 16 + ml;
                bv[mi] = *(const bf16x8*)(Ab + m * 128 + (((ks * 4 + kq) * 16) ^ ((m & 7) << 4)));
            }
            #pragma unroll
            for (int f = 0; f < NF; ++f)
                #pragma unroll
                for (int mi = 0; mi < MF; ++mi)
                    acc[f][mi] = __builtin_amdgcn_mfma_f32_16x16x32_bf16(af[f], bv[mi], acc[f][mi], 0, 0, 0);
        }
    };

    stage(0, 0);
    stage(1, 1);
    asm volatile("s_waitcnt vmcnt(5)" ::: "memory");
    SBAR();

    #pragma unroll 1
    for (int c = 0; c < NC; ++c) {
        mfmaC(c & 1);
        if (c + 2 < NC) {
            SBAR();
            stage(c + 2, c & 1);
            asm volatile("s_waitcnt vmcnt(5)" ::: "memory");
            SBAR();
        } else if (c + 1 < NC) {
            SBAR();
            asm volatile("s_waitcnt vmcnt(0)" ::: "memory");
            SBAR();
        }
    }

    const int nq4 = (lane >> 4) * 4;
    if (!F32OUT) {
        ushort* Y = (ushort*)Yg;
        #pragma unroll
        for (int f = 0; f < NF; ++f) {
            int n4 = n0 + wn0 + f * 16 + nq4;
            float bv0 = bias[BDIV3 ? n4 / 3 : n4];
            float bv1 = bias[BDIV3 ? (n4 + 1) / 3 : n4 + 1];
            float bv2 = bias[BDIV3 ? (n4 + 2) / 3 : n4 + 2];
            float bv3 = bias[BDIV3 ? (n4 + 3) / 3 : n4 + 3];
            #pragma unroll
            for (int mi = 0; mi < MF; ++mi) {
                int m = mbase + mi * 16 + ml;
                float x0 = acc[f][mi][0] + bv0, x1 = acc[f][mi][1] + bv1;
                float x2 = acc[f][mi][2] + bv2, x3 = acc[f][mi][3] + bv3;
                if (RELU) { x0 = fmaxf(x0, 0.f); x1 = fmaxf(x1, 0.f);
                            x2 = fmaxf(x2, 0.f); x3 = fmaxf(x3, 0.f); }
                ushort4 o = {f2bf(x0), f2bf(x1), f2bf(x2), f2bf(x3)};
                *(ushort4*)(Y + (size_t)(m0 + m) * ldy + n4) = o;
            }
        }
    } else {
        float* Y = (float*)Yg;
        #pragma unroll
        for (int f = 0; f < NF; ++f) {
            int nf = n0 + wn0 + f * 16;
            if (nf < 800) {
                int n4 = nf + nq4, sh = n4 & 31;
                float bv0 = bias[n4], bv1 = bias[n4 + 1];
                float bv2 = bias[n4 + 2], bv3 = bias[n4 + 3];
                #pragma unroll
                for (int mi = 0; mi < MF; ++mi) {
                    int m = mbase + mi * 16 + ml;
                    uint32_t mwv = maskg[(size_t)(m0 + m) * 25 + (nf >> 5)];
                    float4 v;
                    v.x = ((mwv >> (sh + 0)) & 1u) ? NEG_HUGE : (acc[f][mi][0] + bv0);
                    v.y = ((mwv >> (sh + 1)) & 1u) ? NEG_HUGE : (acc[f][mi][1] + bv1);
                    v.z = ((mwv >> (sh + 2)) & 1u) ? NEG_HUGE : (acc[f][mi][2] + bv2);
                    v.w = ((mwv >> (sh + 3)) & 1u) ? NEG_HUGE : (acc[f][mi][3] + bv3);
                    *(float4*)(Y + (size_t)(m0 + m) * ldy + n4) = v;
                }
            }
        }
    }
}

__global__ void ws_fail_kernel(float* out) {
    if (threadIdx.x == 0 && blockIdx.x == 0) out[0] = NAN;
}

extern "C" void kernel_launch(void* const* d_in, const int* in_sizes, int n_in,
                              void* d_out, int out_size, void* d_ws, size_t ws_size,
                              hipStream_t stream) {
    const float* state = (const float*)d_in[0];
    const float* w1  = (const float*)d_in[1];
    const float* b1  = (const float*)d_in[2];
    const float* w2  = (const float*)d_in[3];
    const float* b2  = (const float*)d_in[4];
    const float* w3  = (const float*)d_in[5];
    const float* b3  = (const float*)d_in[6];
    const float* wl1 = (const float*)d_in[7];
    const float* bl1 = (const float*)d_in[8];
    const float* wl2 = (const float*)d_in[9];
    const float* bl2 = (const float*)d_in[10];
    float* out = (float*)d_out;

    char* ws = (char*)d_ws;
    size_t off = 0;
    auto carve = [&](size_t bytes) {
        char* p = ws + off;
        off = (off + bytes + 255) & ~(size_t)255;
        return p;
    };
    ushort* W1T  = (ushort*)carve(384ull * 2432 * 2);
    ushort* W2T  = (ushort*)carve(768ull * 384 * 2);
    ushort* W3T  = (ushort*)carve(384ull * 768 * 2);
    ushort* WL1T = (ushort*)carve(192ull * 384 * 2);
    ushort* WL2T = (ushort*)carve(960ull * 192 * 2);
    ushort* X1g  = (ushort*)carve(16384ull * 384 * 2);
    ushort* X2g  = (ushort*)carve(16384ull * 768 * 2);
    ushort* X3g  = (ushort*)carve(16384ull * 384 * 2);
    ushort* X4g  = (ushort*)carve(16384ull * 192 * 2);
    uint32_t* maskg = (uint32_t*)carve(16384ull * 25 * 4);

    if (off > ws_size) {
        ws_fail_kernel<<<1, 64, 0, stream>>>(out);
        return;
    }

    prep_conv_T<<<(384 * 2432 + 255) / 256, 256, 0, stream>>>(w1, W1T, 800, 128, 384, 2432);
    prep_conv_T<<<(768 * 384 + 255) / 256, 256, 0, stream>>>(w2, W2T, 128, 256, 768, 384);
    prep_conv_T<<<(384 * 768 + 255) / 256, 256, 0, stream>>>(w3, W3T, 256, 128, 384, 768);
    prep_lin_T<<<(192 * 384 + 255) / 256, 256, 0, stream>>>(wl1, WL1T, 384, 192, 192);
    prep_lin_T<<<(960 * 192 + 255) / 256, 256, 0, stream>>>(wl2, WL2T, 192, 800, 960);

    // conv1 (fused convert+mask): state -> X1g, maskg
    (void)hipFuncSetAttribute(reinterpret_cast<const void*>(conv1_kernel),
                        hipFuncAttributeMaxDynamicSharedMemorySize, 71936);
    conv1_kernel<<<dim3(256, 2), 512, 71936, stream>>>(state, W1T, b1, X1g, maskg);

    // conv2: X1g[16384,384] @ W2T[768,384] -> X2g
    auto kc2 = glayer3<384, true, true, false>;
    (void)hipFuncSetAttribute(reinterpret_cast<const void*>(kc2),
                        hipFuncAttributeMaxDynamicSharedMemorySize, 81920);
    kc2<<<dim3(128, 4), 512, 81920, stream>>>(X1g, W2T, b2, X2g, 768, nullptr);

    // conv3: X2g[16384,768] @ W3T[384,768] -> X3g
    auto kc3 = glayer3<768, true, true, false>;
    (void)hipFuncSetAttribute(reinterpret_cast<const void*>(kc3),
                        hipFuncAttributeMaxDynamicSharedMemorySize, 81920);
    kc3<<<dim3(128, 2), 512, 81920, stream>>>(X2g, W3T, b3, X3g, 384, nullptr);

    // lin1: X3g[16384,384] @ WL1T[192,384] -> X4g
    auto kc4 = glayer3<384, false, true, false>;
    (void)hipFuncSetAttribute(reinterpret_cast<const void*>(kc4),
                        hipFuncAttributeMaxDynamicSharedMemorySize, 81920);
    kc4<<<dim3(128, 1), 512, 81920, stream>>>(X3g, WL1T, bl1, X4g, 192, nullptr);

    // lin2 + mask: X4g[16384,192] @ WL2T[960,192] -> out[16384,800] f32
    auto kc5 = glayer3<192, false, false, true>;
    (void)hipFuncSetAttribute(reinterpret_cast<const void*>(kc5),
                        hipFuncAttributeMaxDynamicSharedMemorySize, 81920);
    kc5<<<dim3(128, 5), 512, 81920, stream>>>(X4g, WL2T, bl2, out, 800, maskg);
}

// Round 14
// 151.863 us; speedup vs baseline: 1.1256x; 1.1256x over previous
//
#include <hip/hip_runtime.h>
#include <cstdint>
#include <cstddef>
#include <math.h>

typedef short bf16x8 __attribute__((ext_vector_type(8)));
typedef float f32x4 __attribute__((ext_vector_type(4)));
typedef unsigned long long u64;

#define NEG_HUGE (-3.0e38f)

__device__ __forceinline__ ushort f2bf(float x) {
    union { float f; uint32_t u; } a; a.f = x;
    uint32_t r = a.u + 0x7FFF + ((a.u >> 16) & 1);   // RNE
    return (ushort)(r >> 16);
}

__device__ __forceinline__ void gload_lds16(const void* g, void* l) {
    __builtin_amdgcn_global_load_lds(
        (const __attribute__((address_space(1))) uint32_t*)g,
        (__attribute__((address_space(3))) uint32_t*)l, 16, 0, 0);
}

#define SCHED() __builtin_amdgcn_sched_barrier(0)
#define SBAR() do { SCHED(); __builtin_amdgcn_s_barrier(); SCHED(); } while (0)

// ---------------- weight prep ----------------
__global__ void prep_conv_T(const float* __restrict__ w, ushort* __restrict__ WT,
                            int Cin, int Cout, int Nrows, int Kpad) {
    int idx = blockIdx.x * 256 + threadIdx.x;
    if (idx >= Nrows * Kpad) return;
    int n = idx / Kpad, k = idx - n * Kpad;
    float val = 0.f;
    if (k < Cin * 3) {
        int co = n / 3, l = n % 3, ci = k / 3, lx = k % 3;
        int t = lx - l + 1;
        if (t >= 0 && t < 3) val = w[(co * Cin + ci) * 3 + t];
    }
    WT[idx] = f2bf(val);
}

__global__ void prep_lin_T(const float* __restrict__ wl, ushort* __restrict__ WT,
                           int K, int Nreal, int Npad) {
    int idx = blockIdx.x * 256 + threadIdx.x;
    if (idx >= Npad * K) return;
    int n = idx / K, k = idx - n * K;
    WT[idx] = (n < Nreal) ? f2bf(wl[n * K + k]) : (ushort)0;
}

// ---------------- conv1: fused convert + mask + GEMM, counted depth-2 ----------------
// 256 blocks x 64 rows, full N=384 (state read ONCE). 8 waves (2M x 4N): MF=2, NF=6.
// Queue algebra (verified B0/B1/steady/tail): per chunk outstanding at the wait is
// W(c)6, S(c+1)2, W(c+1)6, S(c+2)2 = 16; vmcnt(10) drains exactly W(c) [1 chunk aged,
// L2] and leaves S(c+1) in flight [HBM, waited by compiler at stage_write(c+1), ~2
// chunk-times aged]. Prologue order S(0) < W(0) < S(1) so B(0)'s vmcnt(10) fully
// drains W(0).
__global__ __launch_bounds__(512, 2)
void conv1_kernel(const float* __restrict__ state, const ushort* __restrict__ W1T,
                  const float* __restrict__ b1, ushort* __restrict__ X1g,
                  uint32_t* __restrict__ maskg)
{
    extern __shared__ char lds[];
    char* BF0 = lds;                                // 64*128 = 8192
    char* BF1 = lds + 8192;
    char* Wb0 = lds + 16384;                        // 384*128 = 49152
    char* Wb1 = lds + 65536;
    uint32_t* maskw = (uint32_t*)(lds + 114688);    // [64][25] = 6400

    const int tid = threadIdx.x, lane = tid & 63, wid = tid >> 6;
    const int m0 = blockIdx.x * 64;
    const int ml = lane & 15, kq = lane >> 4;
    const int mbase = (wid >> 2) * 32;              // 2 M-waves
    const int wn0 = (wid & 3) * 96;                 // 4 N-waves x 96 cols

    const int srow = tid >> 3, seg = tid & 7;       // 8 threads/row, 8 floats each
    const float* sbase = state + (size_t)(m0 + srow) * 2400 + seg * 8;

    f32x4 acc[6][2];
    #pragma unroll
    for (int f = 0; f < 6; ++f)
        #pragma unroll
        for (int mi = 0; mi < 2; ++mi) acc[f][mi] = (f32x4){0.f, 0.f, 0.f, 0.f};

    auto loadS = [&](float4 (&sv)[2], int c) {
        int kb = c * 64 + seg * 8;
        if (kb < 2400) {
            sv[0] = *(const float4*)(sbase + c * 64);
            sv[1] = *(const float4*)(sbase + c * 64 + 4);
        } else {
            sv[0] = (float4){0.f, 0.f, 0.f, 0.f};
            sv[1] = (float4){0.f, 0.f, 0.f, 0.f};
        }
    };
    auto stage_write = [&](float4 (&sv)[2], int c, char* dst) {
        float fv[8] = {sv[0].x, sv[0].y, sv[0].z, sv[0].w,
                       sv[1].x, sv[1].y, sv[1].z, sv[1].w};
        bf16x8 h;
        #pragma unroll
        for (int j = 0; j < 8; ++j) h[j] = (short)f2bf(fv[j]);
        *(bf16x8*)(dst + srow * 128 + ((seg * 16) ^ ((srow & 7) << 4))) = h;
        int kbase = c * 64 + seg * 8;
        int kmod = kbase % 3;
        uint32_t* mrow = &maskw[srow * 25];
        #define MCHK(J) { if (fv[J] != 0.0f) { int a = (kbase + (J)) / 3; \
                          atomicOr(&mrow[a >> 5], 1u << (a & 31)); } }
        if (kmod == 0)      { MCHK(2) MCHK(5) }
        else if (kmod == 1) { MCHK(1) MCHK(4) MCHK(7) }
        else                { MCHK(0) MCHK(3) MCHK(6) }
        #undef MCHK
    };
    auto loadW = [&](int c, char* dst) {            // 48KB: 384 rows x 64 k
        #pragma unroll
        for (int i = 0; i < 6; ++i) {
            int s = i * 512 + tid;
            int r = s >> 3, o8 = s & 7;
            gload_lds16(W1T + (size_t)r * 2432 + c * 64 + ((o8 ^ (r & 7)) * 8),
                        dst + s * 16);
        }
    };
    auto mfmaC = [&](const char* wb, const char* sb) {
        #pragma unroll
        for (int ks = 0; ks < 2; ++ks) {
            bf16x8 af[6], bv[2];
            #pragma unroll
            for (int f = 0; f < 6; ++f) {
                int n = wn0 + f * 16 + ml;
                af[f] = *(const bf16x8*)(wb + n * 128 + (((ks * 4 + kq) * 16) ^ ((n & 7) << 4)));
            }
            #pragma unroll
            for (int mi = 0; mi < 2; ++mi) {
                int m = mbase + mi * 16 + ml;
                bv[mi] = *(const bf16x8*)(sb + m * 128 + (((ks * 4 + kq) * 16) ^ ((m & 7) << 4)));
            }
            #pragma unroll
            for (int f = 0; f < 6; ++f)
                #pragma unroll
                for (int mi = 0; mi < 2; ++mi)
                    acc[f][mi] = __builtin_amdgcn_mfma_f32_16x16x32_bf16(af[f], bv[mi], acc[f][mi], 0, 0, 0);
        }
    };

    for (int i = tid; i < 64 * 25; i += 512) maskw[i] = 0;
    float4 svA[2], svB[2];
    // prologue issue order MUST be S(0), W(0), S(1)  (see header)
    loadS(svA, 0);
    loadW(0, Wb0);
    loadS(svB, 1);
    SCHED();
    asm volatile("s_waitcnt lgkmcnt(0)" ::: "memory");
    SBAR();    // mask zeros visible

    #define BODY(SV, C, SB, WBC, WBN) do {                                   \
        stage_write(SV, (C), SB);                                            \
        SCHED();                                                             \
        asm volatile("s_waitcnt lgkmcnt(0)" ::: "memory");                   \
        SBAR();                                                              \
        loadW(((C) + 1 > 37) ? 37 : (C) + 1, WBN);                           \
        loadS(SV, ((C) + 2 > 37) ? 37 : (C) + 2);                            \
        SCHED();                                                             \
        asm volatile("s_waitcnt vmcnt(10)" ::: "memory");                    \
        SBAR();                                                              \
        mfmaC(WBC, SB);                                                      \
    } while (0)

    #pragma unroll 1
    for (int p = 0; p < 19; ++p) {
        BODY(svA, 2 * p,     BF0, Wb0, Wb1);
        BODY(svB, 2 * p + 1, BF1, Wb1, Wb0);
    }
    #undef BODY

    asm volatile("s_waitcnt vmcnt(0) lgkmcnt(0)" ::: "memory");
    SBAR();

    // epilogue -> X1g [16384][384] bf16 row-major
    {
        const int nq4 = (lane >> 4) * 4;
        #pragma unroll
        for (int f = 0; f < 6; ++f) {
            int n4 = wn0 + f * 16 + nq4;
            float bv0 = b1[n4 / 3], bv1 = b1[(n4 + 1) / 3];
            float bv2 = b1[(n4 + 2) / 3], bv3 = b1[(n4 + 3) / 3];
            #pragma unroll
            for (int mi = 0; mi < 2; ++mi) {
                int m = mbase + mi * 16 + ml;
                ushort4 o;
                o.x = f2bf(fmaxf(acc[f][mi][0] + bv0, 0.f));
                o.y = f2bf(fmaxf(acc[f][mi][1] + bv1, 0.f));
                o.z = f2bf(fmaxf(acc[f][mi][2] + bv2, 0.f));
                o.w = f2bf(fmaxf(acc[f][mi][3] + bv3, 0.f));
                *(ushort4*)(X1g + (size_t)(m0 + m) * 384 + n4) = o;
            }
        }
    }

    // finalize combined mask: visited | user_any | chan_full (one thread per sample)
    if (tid < 64) {
        uint32_t* mw = &maskw[tid * 25];
        const u64 M40 = (1ull << 40) - 1;
        u64 ua = 0; uint32_t cf = 0;
        #pragma unroll
        for (int g = 0; g < 5; ++g) {
            uint32_t w0 = mw[5*g], w1 = mw[5*g+1], w2 = mw[5*g+2], w3 = mw[5*g+3], w4 = mw[5*g+4];
            u64 c0 = ( (u64)w0        | ((u64)w1 << 32)) & M40;
            u64 c1 = (((u64)w1 >> 8)  | ((u64)w2 << 24)) & M40;
            u64 c2 = (((u64)w2 >> 16) | ((u64)w3 << 16)) & M40;
            u64 c3 = (((u64)w3 >> 24) | ((u64)w4 << 8))  & M40;
            ua |= c0 | c1 | c2 | c3;
            if (__popcll(c0) >= 2) cf |= 1u << (4*g);
            if (__popcll(c1) >= 2) cf |= 1u << (4*g+1);
            if (__popcll(c2) >= 2) cf |= 1u << (4*g+2);
            if (__popcll(c3) >= 2) cf |= 1u << (4*g+3);
        }
        uint32_t* mg = maskg + (size_t)(m0 + tid) * 25;
        #pragma unroll
        for (int g = 0; g < 5; ++g) {
            uint32_t w0 = mw[5*g], w1 = mw[5*g+1], w2 = mw[5*g+2], w3 = mw[5*g+3], w4 = mw[5*g+4];
            u64 c0 = ( (u64)w0        | ((u64)w1 << 32)) & M40;
            u64 c1 = (((u64)w1 >> 8)  | ((u64)w2 << 24)) & M40;
            u64 c2 = (((u64)w2 >> 16) | ((u64)w3 << 16)) & M40;
            u64 c3 = (((u64)w3 >> 24) | ((u64)w4 << 8))  & M40;
            u64 m0v = c0 | ua | (((cf >> (4*g))     & 1u) ? M40 : 0ull);
            u64 m1v = c1 | ua | (((cf >> (4*g + 1)) & 1u) ? M40 : 0ull);
            u64 m2v = c2 | ua | (((cf >> (4*g + 2)) & 1u) ? M40 : 0ull);
            u64 m3v = c3 | ua | (((cf >> (4*g + 3)) & 1u) ? M40 : 0ull);
            mg[5*g]   = (uint32_t)m0v;
            mg[5*g+1] = (uint32_t)(m0v >> 32) | (uint32_t)(m1v << 8);
            mg[5*g+2] = (uint32_t)(m1v >> 24) | (uint32_t)(m2v << 16);
            mg[5*g+3] = (uint32_t)(m2v >> 16) | (uint32_t)(m3v << 24);
            mg[5*g+4] = (uint32_t)(m3v >> 8);
        }
    }
}

// ---------------- uniform GEMM layer, depth-2 counted pipeline (unchanged) ----------------
template<int K, bool BDIV3, bool RELU, bool F32OUT>
__global__ __launch_bounds__(512, 4)
void glayer3(const ushort* __restrict__ Ag, const ushort* __restrict__ WTg,
             const float* __restrict__ bias, void* __restrict__ Yg, int ldy,
             const uint32_t* __restrict__ maskg)
{
    constexpr int MF = 4, NF = 3;
    constexpr int MT = 128, NT = 192;
    constexpr int NC = K / 64;
    constexpr int ABYTES = MT * 128;
    constexpr int WBYTES = NT * 128;
    static_assert(NC >= 3, "pipeline assumes >=3 chunks");
    extern __shared__ char lds[];

    const int tid = threadIdx.x, lane = tid & 63, wid = tid >> 6;
    const int m0 = blockIdx.x * MT;
    const int n0 = blockIdx.y * NT;
    const int ml = lane & 15, kq = lane >> 4;
    const int mw = wid >> 2, nw = wid & 3;
    const int mbase = mw * MF * 16;
    const int wn0 = nw * NF * 16;

    f32x4 acc[NF][MF];
    #pragma unroll
    for (int f = 0; f < NF; ++f)
        #pragma unroll
        for (int mi = 0; mi < MF; ++mi) acc[f][mi] = (f32x4){0.f, 0.f, 0.f, 0.f};

    auto stage = [&](int c, int b) {
        char* Ab = lds + b * ABYTES;
        char* Wb = lds + 2 * ABYTES + b * WBYTES;
        #pragma unroll
        for (int i = 0; i < 2; ++i) {
            int s = i * 512 + tid;
            int r = s >> 3, o8 = s & 7;
            gload_lds16(Ag + (size_t)(m0 + r) * K + c * 64 + ((o8 ^ (r & 7)) * 8),
                        Ab + s * 16);
        }
        #pragma unroll
        for (int i = 0; i < 3; ++i) {
            int s = i * 512 + tid;
            int r = s >> 3, o8 = s & 7;
            gload_lds16(WTg + (size_t)(n0 + r) * K + c * 64 + ((o8 ^ (r & 7)) * 8),
                        Wb + s * 16);
        }
    };
    auto mfmaC = [&](int b) {
        const char* Ab = lds + b * ABYTES;
        const char* Wb = lds + 2 * ABYTES + b * WBYTES;
        #pragma unroll
        for (int ks = 0; ks < 2; ++ks) {
            bf16x8 af[NF], bv[MF];
            #pragma unroll
            for (int f = 0; f < NF; ++f) {
                int n = wn0 + f * 16 + ml;
                af[f] = *(const bf16x8*)(Wb + n * 128 + (((ks * 4 + kq) * 16) ^ ((n & 7) << 4)));
            }
            #pragma unroll
            for (int mi = 0; mi < MF; ++mi) {
                int m = mbase + mi * 16 + ml;
                bv[mi] = *(const bf16x8*)(Ab + m * 128 + (((ks * 4 + kq) * 16) ^ ((m & 7) << 4)));
            }
            #pragma unroll
            for (int f = 0; f < NF; ++f)
                #pragma unroll
                for (int mi = 0; mi < MF; ++mi)
                    acc[f][mi] = __builtin_amdgcn_mfma_f32_16x16x32_bf16(af[f], bv[mi], acc[f][mi], 0, 0, 0);
        }
    };

    stage(0, 0);
    stage(1, 1);
    asm volatile("s_waitcnt vmcnt(5)" ::: "memory");
    SBAR();

    #pragma unroll 1
    for (int c = 0; c < NC; ++c) {
        mfmaC(c & 1);
        if (c + 2 < NC) {
            SBAR();
            stage(c + 2, c & 1);
            asm volatile("s_waitcnt vmcnt(5)" ::: "memory");
            SBAR();
        } else if (c + 1 < NC) {
            SBAR();
            asm volatile("s_waitcnt vmcnt(0)" ::: "memory");
            SBAR();
        }
    }

    const int nq4 = (lane >> 4) * 4;
    if (!F32OUT) {
        ushort* Y = (ushort*)Yg;
        #pragma unroll
        for (int f = 0; f < NF; ++f) {
            int n4 = n0 + wn0 + f * 16 + nq4;
            float bv0 = bias[BDIV3 ? n4 / 3 : n4];
            float bv1 = bias[BDIV3 ? (n4 + 1) / 3 : n4 + 1];
            float bv2 = bias[BDIV3 ? (n4 + 2) / 3 : n4 + 2];
            float bv3 = bias[BDIV3 ? (n4 + 3) / 3 : n4 + 3];
            #pragma unroll
            for (int mi = 0; mi < MF; ++mi) {
                int m = mbase + mi * 16 + ml;
                float x0 = acc[f][mi][0] + bv0, x1 = acc[f][mi][1] + bv1;
                float x2 = acc[f][mi][2] + bv2, x3 = acc[f][mi][3] + bv3;
                if (RELU) { x0 = fmaxf(x0, 0.f); x1 = fmaxf(x1, 0.f);
                            x2 = fmaxf(x2, 0.f); x3 = fmaxf(x3, 0.f); }
                ushort4 o = {f2bf(x0), f2bf(x1), f2bf(x2), f2bf(x3)};
                *(ushort4*)(Y + (size_t)(m0 + m) * ldy + n4) = o;
            }
        }
    } else {
        float* Y = (float*)Yg;
        #pragma unroll
        for (int f = 0; f < NF; ++f) {
            int nf = n0 + wn0 + f * 16;
            if (nf < 800) {
                int n4 = nf + nq4, sh = n4 & 31;
                float bv0 = bias[n4], bv1 = bias[n4 + 1];
                float bv2 = bias[n4 + 2], bv3 = bias[n4 + 3];
                #pragma unroll
                for (int mi = 0; mi < MF; ++mi) {
                    int m = mbase + mi * 16 + ml;
                    uint32_t mwv = maskg[(size_t)(m0 + m) * 25 + (nf >> 5)];
                    float4 v;
                    v.x = ((mwv >> (sh + 0)) & 1u) ? NEG_HUGE : (acc[f][mi][0] + bv0);
                    v.y = ((mwv >> (sh + 1)) & 1u) ? NEG_HUGE : (acc[f][mi][1] + bv1);
                    v.z = ((mwv >> (sh + 2)) & 1u) ? NEG_HUGE : (acc[f][mi][2] + bv2);
                    v.w = ((mwv >> (sh + 3)) & 1u) ? NEG_HUGE : (acc[f][mi][3] + bv3);
                    *(float4*)(Y + (size_t)(m0 + m) * ldy + n4) = v;
                }
            }
        }
    }
}

__global__ void ws_fail_kernel(float* out) {
    if (threadIdx.x == 0 && blockIdx.x == 0) out[0] = NAN;
}

extern "C" void kernel_launch(void* const* d_in, const int* in_sizes, int n_in,
                              void* d_out, int out_size, void* d_ws, size_t ws_size,
                              hipStream_t stream) {
    const float* state = (const float*)d_in[0];
    const float* w1  = (const float*)d_in[1];
    const float* b1  = (const float*)d_in[2];
    const float* w2  = (const float*)d_in[3];
    const float* b2  = (const float*)d_in[4];
    const float* w3  = (const float*)d_in[5];
    const float* b3  = (const float*)d_in[6];
    const float* wl1 = (const float*)d_in[7];
    const float* bl1 = (const float*)d_in[8];
    const float* wl2 = (const float*)d_in[9];
    const float* bl2 = (const float*)d_in[10];
    float* out = (float*)d_out;

    char* ws = (char*)d_ws;
    size_t off = 0;
    auto carve = [&](size_t bytes) {
        char* p = ws + off;
        off = (off + bytes + 255) & ~(size_t)255;
        return p;
    };
    ushort* W1T  = (ushort*)carve(384ull * 2432 * 2);
    ushort* W2T  = (ushort*)carve(768ull * 384 * 2);
    ushort* W3T  = (ushort*)carve(384ull * 768 * 2);
    ushort* WL1T = (ushort*)carve(192ull * 384 * 2);
    ushort* WL2T = (ushort*)carve(960ull * 192 * 2);
    ushort* X1g  = (ushort*)carve(16384ull * 384 * 2);
    ushort* X2g  = (ushort*)carve(16384ull * 768 * 2);
    ushort* X3g  = (ushort*)carve(16384ull * 384 * 2);
    ushort* X4g  = (ushort*)carve(16384ull * 192 * 2);
    uint32_t* maskg = (uint32_t*)carve(16384ull * 25 * 4);

    if (off > ws_size) {
        ws_fail_kernel<<<1, 64, 0, stream>>>(out);
        return;
    }

    prep_conv_T<<<(384 * 2432 + 255) / 256, 256, 0, stream>>>(w1, W1T, 800, 128, 384, 2432);
    prep_conv_T<<<(768 * 384 + 255) / 256, 256, 0, stream>>>(w2, W2T, 128, 256, 768, 384);
    prep_conv_T<<<(384 * 768 + 255) / 256, 256, 0, stream>>>(w3, W3T, 256, 128, 384, 768);
    prep_lin_T<<<(192 * 384 + 255) / 256, 256, 0, stream>>>(wl1, WL1T, 384, 192, 192);
    prep_lin_T<<<(960 * 192 + 255) / 256, 256, 0, stream>>>(wl2, WL2T, 192, 800, 960);

    // conv1 (fused convert+mask): state -> X1g, maskg
    (void)hipFuncSetAttribute(reinterpret_cast<const void*>(conv1_kernel),
                        hipFuncAttributeMaxDynamicSharedMemorySize, 121088);
    conv1_kernel<<<256, 512, 121088, stream>>>(state, W1T, b1, X1g, maskg);

    // conv2: X1g[16384,384] @ W2T[768,384] -> X2g
    auto kc2 = glayer3<384, true, true, false>;
    (void)hipFuncSetAttribute(reinterpret_cast<const void*>(kc2),
                        hipFuncAttributeMaxDynamicSharedMemorySize, 81920);
    kc2<<<dim3(128, 4), 512, 81920, stream>>>(X1g, W2T, b2, X2g, 768, nullptr);

    // conv3: X2g[16384,768] @ W3T[384,768] -> X3g
    auto kc3 = glayer3<768, true, true, false>;
    (void)hipFuncSetAttribute(reinterpret_cast<const void*>(kc3),
                        hipFuncAttributeMaxDynamicSharedMemorySize, 81920);
    kc3<<<dim3(128, 2), 512, 81920, stream>>>(X2g, W3T, b3, X3g, 384, nullptr);

    // lin1: X3g[16384,384] @ WL1T[192,384] -> X4g
    auto kc4 = glayer3<384, false, true, false>;
    (void)hipFuncSetAttribute(reinterpret_cast<const void*>(kc4),
                        hipFuncAttributeMaxDynamicSharedMemorySize, 81920);
    kc4<<<dim3(128, 1), 512, 81920, stream>>>(X3g, WL1T, bl1, X4g, 192, nullptr);

    // lin2 + mask: X4g[16384,192] @ WL2T[960,192] -> out[16384,800] f32
    auto kc5 = glayer3<192, false, false, true>;
    (void)hipFuncSetAttribute(reinterpret_cast<const void*>(kc5),
                        hipFuncAttributeMaxDynamicSharedMemorySize, 81920);
    kc5<<<dim3(128, 5), 512, 81920, stream>>>(X4g, WL2T, bl2, out, 800, maskg);
}

// Round 15
// 141.052 us; speedup vs baseline: 1.2119x; 1.0766x over previous
//
#include <hip/hip_runtime.h>
#include <cstdint>
#include <cstddef>
#include <math.h>

typedef short bf16x8 __attribute__((ext_vector_type(8)));
typedef float f32x4 __attribute__((ext_vector_type(4)));
typedef unsigned long long u64;

#define NEG_HUGE (-3.0e38f)

__device__ __forceinline__ ushort f2bf(float x) {
    union { float f; uint32_t u; } a; a.f = x;
    uint32_t r = a.u + 0x7FFF + ((a.u >> 16) & 1);   // RNE
    return (ushort)(r >> 16);
}

__device__ __forceinline__ void gload_lds16(const void* g, void* l) {
    __builtin_amdgcn_global_load_lds(
        (const __attribute__((address_space(1))) uint32_t*)g,
        (__attribute__((address_space(3))) uint32_t*)l, 16, 0, 0);
}

#define SCHED() __builtin_amdgcn_sched_barrier(0)
#define SBAR() do { SCHED(); __builtin_amdgcn_s_barrier(); SCHED(); } while (0)

// ---------------- weight prep ----------------
__global__ void prep_conv_T(const float* __restrict__ w, ushort* __restrict__ WT,
                            int Cin, int Cout, int Nrows, int Kpad) {
    int idx = blockIdx.x * 256 + threadIdx.x;
    if (idx >= Nrows * Kpad) return;
    int n = idx / Kpad, k = idx - n * Kpad;
    float val = 0.f;
    if (k < Cin * 3) {
        int co = n / 3, l = n % 3, ci = k / 3, lx = k % 3;
        int t = lx - l + 1;
        if (t >= 0 && t < 3) val = w[(co * Cin + ci) * 3 + t];
    }
    WT[idx] = f2bf(val);
}

__global__ void prep_lin_T(const float* __restrict__ wl, ushort* __restrict__ WT,
                           int K, int Nreal, int Npad) {
    int idx = blockIdx.x * 256 + threadIdx.x;
    if (idx >= Npad * K) return;
    int n = idx / K, k = idx - n * K;
    WT[idx] = (n < Nreal) ? f2bf(wl[n * K + k]) : (ushort)0;
}

// ---------------- conv1: fused convert + mask + GEMM, 2 blocks/CU ----------------
// grid (256 m-tiles, 2 n-halves). Block: 64 rows x 192 cols, BK=64, 38 chunks.
// LDS 70.7KB -> 2 blocks/CU (the m114 inter-block overlap is the lever; R8 anchor).
// Queue algebra (verified incl. clamped tail): at the wait, outstanding =
// W(c)3, S(c+1)2, W(c+1)3, S(c+2)2 = 10; vmcnt(7) drains exactly W(c) [1 chunk
// aged, L2]. S(c+1) is drained by the COMPILER's register wait at
// stage_write(c+1), by which point it is 2 chunk-times old. Prologue issue order
// MUST be S(0) < W(0) < S(1).
__global__ __launch_bounds__(512, 4)
void conv1_kernel(const float* __restrict__ state, const ushort* __restrict__ W1T,
                  const float* __restrict__ b1, ushort* __restrict__ X1g,
                  uint32_t* __restrict__ maskg)
{
    extern __shared__ char lds[];
    char* BF0 = lds;                                // 64*128 = 8192
    char* BF1 = lds + 8192;
    char* Wb0 = lds + 16384;                        // 192*128 = 24576
    char* Wb1 = lds + 40960;
    uint32_t* maskw = (uint32_t*)(lds + 65536);     // [64][25] = 6400

    const int tid = threadIdx.x, lane = tid & 63, wid = tid >> 6;
    const int m0 = blockIdx.x * 64;
    const int n0 = blockIdx.y * 192;
    const bool domask = (blockIdx.y == 0);
    const int ml = lane & 15, kq = lane >> 4;
    const int mbase = (wid >> 2) * 32;              // 2 M-waves
    const int wn0 = (wid & 3) * 48;                 // 4 N-waves x 48 cols

    const int srow = tid >> 3, seg = tid & 7;       // 8 threads/row, 8 floats each
    const float* sbase = state + (size_t)(m0 + srow) * 2400 + seg * 8;

    f32x4 acc[3][2];
    #pragma unroll
    for (int f = 0; f < 3; ++f)
        #pragma unroll
        for (int mi = 0; mi < 2; ++mi) acc[f][mi] = (f32x4){0.f, 0.f, 0.f, 0.f};

    auto loadS = [&](float4 (&sv)[2], int c) {
        int kb = c * 64 + seg * 8;
        if (kb < 2400) {
            sv[0] = *(const float4*)(sbase + c * 64);
            sv[1] = *(const float4*)(sbase + c * 64 + 4);
        } else {
            sv[0] = (float4){0.f, 0.f, 0.f, 0.f};
            sv[1] = (float4){0.f, 0.f, 0.f, 0.f};
        }
    };
    auto stage_write = [&](float4 (&sv)[2], int c, char* dst) {
        float fv[8] = {sv[0].x, sv[0].y, sv[0].z, sv[0].w,
                       sv[1].x, sv[1].y, sv[1].z, sv[1].w};
        bf16x8 h;
        #pragma unroll
        for (int j = 0; j < 8; ++j) h[j] = (short)f2bf(fv[j]);
        *(bf16x8*)(dst + srow * 128 + ((seg * 16) ^ ((srow & 7) << 4))) = h;
        if (domask) {
            int kbase = c * 64 + seg * 8;
            int kmod = kbase % 3;
            uint32_t* mrow = &maskw[srow * 25];
            #define MCHK(J) { if (fv[J] != 0.0f) { int a = (kbase + (J)) / 3; \
                              atomicOr(&mrow[a >> 5], 1u << (a & 31)); } }
            if (kmod == 0)      { MCHK(2) MCHK(5) }
            else if (kmod == 1) { MCHK(1) MCHK(4) MCHK(7) }
            else                { MCHK(0) MCHK(3) MCHK(6) }
            #undef MCHK
        }
    };
    auto loadW = [&](int c, char* dst) {            // 24KB: rows n0..n0+191, k-chunk c
        #pragma unroll
        for (int i = 0; i < 3; ++i) {
            int s = i * 512 + tid;
            int r = s >> 3, o8 = s & 7;
            gload_lds16(W1T + (size_t)(n0 + r) * 2432 + c * 64 + ((o8 ^ (r & 7)) * 8),
                        dst + s * 16);
        }
    };
    auto mfmaC = [&](const char* wb, const char* sb) {
        #pragma unroll
        for (int ks = 0; ks < 2; ++ks) {
            bf16x8 af[3], bv[2];
            #pragma unroll
            for (int f = 0; f < 3; ++f) {
                int n = wn0 + f * 16 + ml;
                af[f] = *(const bf16x8*)(wb + n * 128 + (((ks * 4 + kq) * 16) ^ ((n & 7) << 4)));
            }
            #pragma unroll
            for (int mi = 0; mi < 2; ++mi) {
                int m = mbase + mi * 16 + ml;
                bv[mi] = *(const bf16x8*)(sb + m * 128 + (((ks * 4 + kq) * 16) ^ ((m & 7) << 4)));
            }
            #pragma unroll
            for (int f = 0; f < 3; ++f)
                #pragma unroll
                for (int mi = 0; mi < 2; ++mi)
                    acc[f][mi] = __builtin_amdgcn_mfma_f32_16x16x32_bf16(af[f], bv[mi], acc[f][mi], 0, 0, 0);
        }
    };

    for (int i = tid; i < 64 * 25; i += 512) maskw[i] = 0;
    float4 svA[2], svB[2];
    // prologue issue order MUST be S(0), W(0), S(1)
    loadS(svA, 0);
    loadW(0, Wb0);
    loadS(svB, 1);
    SCHED();
    asm volatile("s_waitcnt lgkmcnt(0)" ::: "memory");
    SBAR();    // mask zeros visible

    #define BODY(SV, C, SB, WBC, WBN) do {                                   \
        stage_write(SV, (C), SB);                                            \
        SCHED();                                                             \
        asm volatile("s_waitcnt lgkmcnt(0)" ::: "memory");                   \
        SBAR();                                                              \
        loadW(((C) + 1 > 37) ? 37 : (C) + 1, WBN);                           \
        loadS(SV, ((C) + 2 > 37) ? 37 : (C) + 2);                            \
        SCHED();                                                             \
        asm volatile("s_waitcnt vmcnt(7)" ::: "memory");                     \
        SBAR();                                                              \
        mfmaC(WBC, SB);                                                      \
    } while (0)

    #pragma unroll 1
    for (int p = 0; p < 19; ++p) {
        BODY(svA, 2 * p,     BF0, Wb0, Wb1);
        BODY(svB, 2 * p + 1, BF1, Wb1, Wb0);
    }
    #undef BODY

    asm volatile("s_waitcnt vmcnt(0) lgkmcnt(0)" ::: "memory");
    SBAR();

    // epilogue -> X1g [16384][384] bf16, cols n0..n0+191
    {
        const int nq4 = (lane >> 4) * 4;
        #pragma unroll
        for (int f = 0; f < 3; ++f) {
            int n4 = n0 + wn0 + f * 16 + nq4;
            float bv0 = b1[n4 / 3], bv1 = b1[(n4 + 1) / 3];
            float bv2 = b1[(n4 + 2) / 3], bv3 = b1[(n4 + 3) / 3];
            #pragma unroll
            for (int mi = 0; mi < 2; ++mi) {
                int m = mbase + mi * 16 + ml;
                ushort4 o;
                o.x = f2bf(fmaxf(acc[f][mi][0] + bv0, 0.f));
                o.y = f2bf(fmaxf(acc[f][mi][1] + bv1, 0.f));
                o.z = f2bf(fmaxf(acc[f][mi][2] + bv2, 0.f));
                o.w = f2bf(fmaxf(acc[f][mi][3] + bv3, 0.f));
                *(ushort4*)(X1g + (size_t)(m0 + m) * 384 + n4) = o;
            }
        }
    }

    // finalize combined mask (y==0 blocks only; one thread per sample)
    if (domask && tid < 64) {
        uint32_t* mw = &maskw[tid * 25];
        const u64 M40 = (1ull << 40) - 1;
        u64 ua = 0; uint32_t cf = 0;
        #pragma unroll
        for (int g = 0; g < 5; ++g) {
            uint32_t w0 = mw[5*g], w1 = mw[5*g+1], w2 = mw[5*g+2], w3 = mw[5*g+3], w4 = mw[5*g+4];
            u64 c0 = ( (u64)w0        | ((u64)w1 << 32)) & M40;
            u64 c1 = (((u64)w1 >> 8)  | ((u64)w2 << 24)) & M40;
            u64 c2 = (((u64)w2 >> 16) | ((u64)w3 << 16)) & M40;
            u64 c3 = (((u64)w3 >> 24) | ((u64)w4 << 8))  & M40;
            ua |= c0 | c1 | c2 | c3;
            if (__popcll(c0) >= 2) cf |= 1u << (4*g);
            if (__popcll(c1) >= 2) cf |= 1u << (4*g+1);
            if (__popcll(c2) >= 2) cf |= 1u << (4*g+2);
            if (__popcll(c3) >= 2) cf |= 1u << (4*g+3);
        }
        uint32_t* mg = maskg + (size_t)(m0 + tid) * 25;
        #pragma unroll
        for (int g = 0; g < 5; ++g) {
            uint32_t w0 = mw[5*g], w1 = mw[5*g+1], w2 = mw[5*g+2], w3 = mw[5*g+3], w4 = mw[5*g+4];
            u64 c0 = ( (u64)w0        | ((u64)w1 << 32)) & M40;
            u64 c1 = (((u64)w1 >> 8)  | ((u64)w2 << 24)) & M40;
            u64 c2 = (((u64)w2 >> 16) | ((u64)w3 << 16)) & M40;
            u64 c3 = (((u64)w3 >> 24) | ((u64)w4 << 8))  & M40;
            u64 m0v = c0 | ua | (((cf >> (4*g))     & 1u) ? M40 : 0ull);
            u64 m1v = c1 | ua | (((cf >> (4*g + 1)) & 1u) ? M40 : 0ull);
            u64 m2v = c2 | ua | (((cf >> (4*g + 2)) & 1u) ? M40 : 0ull);
            u64 m3v = c3 | ua | (((cf >> (4*g + 3)) & 1u) ? M40 : 0ull);
            mg[5*g]   = (uint32_t)m0v;
            mg[5*g+1] = (uint32_t)(m0v >> 32) | (uint32_t)(m1v << 8);
            mg[5*g+2] = (uint32_t)(m1v >> 24) | (uint32_t)(m2v << 16);
            mg[5*g+3] = (uint32_t)(m2v >> 16) | (uint32_t)(m3v << 24);
            mg[5*g+4] = (uint32_t)(m3v >> 8);
        }
    }
}

// ---------------- uniform GEMM layer, depth-2 counted pipeline (unchanged) ----------------
template<int K, bool BDIV3, bool RELU, bool F32OUT>
__global__ __launch_bounds__(512, 4)
void glayer3(const ushort* __restrict__ Ag, const ushort* __restrict__ WTg,
             const float* __restrict__ bias, void* __restrict__ Yg, int ldy,
             const uint32_t* __restrict__ maskg)
{
    constexpr int MF = 4, NF = 3;
    constexpr int MT = 128, NT = 192;
    constexpr int NC = K / 64;
    constexpr int ABYTES = MT * 128;
    constexpr int WBYTES = NT * 128;
    static_assert(NC >= 3, "pipeline assumes >=3 chunks");
    extern __shared__ char lds[];

    const int tid = threadIdx.x, lane = tid & 63, wid = tid >> 6;
    const int m0 = blockIdx.x * MT;
    const int n0 = blockIdx.y * NT;
    const int ml = lane & 15, kq = lane >> 4;
    const int mw = wid >> 2, nw = wid & 3;
    const int mbase = mw * MF * 16;
    const int wn0 = nw * NF * 16;

    f32x4 acc[NF][MF];
    #pragma unroll
    for (int f = 0; f < NF; ++f)
        #pragma unroll
        for (int mi = 0; mi < MF; ++mi) acc[f][mi] = (f32x4){0.f, 0.f, 0.f, 0.f};

    auto stage = [&](int c, int b) {
        char* Ab = lds + b * ABYTES;
        char* Wb = lds + 2 * ABYTES + b * WBYTES;
        #pragma unroll
        for (int i = 0; i < 2; ++i) {
            int s = i * 512 + tid;
            int r = s >> 3, o8 = s & 7;
            gload_lds16(Ag + (size_t)(m0 + r) * K + c * 64 + ((o8 ^ (r & 7)) * 8),
                        Ab + s * 16);
        }
        #pragma unroll
        for (int i = 0; i < 3; ++i) {
            int s = i * 512 + tid;
            int r = s >> 3, o8 = s & 7;
            gload_lds16(WTg + (size_t)(n0 + r) * K + c * 64 + ((o8 ^ (r & 7)) * 8),
                        Wb + s * 16);
        }
    };
    auto mfmaC = [&](int b) {
        const char* Ab = lds + b * ABYTES;
        const char* Wb = lds + 2 * ABYTES + b * WBYTES;
        #pragma unroll
        for (int ks = 0; ks < 2; ++ks) {
            bf16x8 af[NF], bv[MF];
            #pragma unroll
            for (int f = 0; f < NF; ++f) {
                int n = wn0 + f * 16 + ml;
                af[f] = *(const bf16x8*)(Wb + n * 128 + (((ks * 4 + kq) * 16) ^ ((n & 7) << 4)));
            }
            #pragma unroll
            for (int mi = 0; mi < MF; ++mi) {
                int m = mbase + mi * 16 + ml;
                bv[mi] = *(const bf16x8*)(Ab + m * 128 + (((ks * 4 + kq) * 16) ^ ((m & 7) << 4)));
            }
            #pragma unroll
            for (int f = 0; f < NF; ++f)
                #pragma unroll
                for (int mi = 0; mi < MF; ++mi)
                    acc[f][mi] = __builtin_amdgcn_mfma_f32_16x16x32_bf16(af[f], bv[mi], acc[f][mi], 0, 0, 0);
        }
    };

    stage(0, 0);
    stage(1, 1);
    asm volatile("s_waitcnt vmcnt(5)" ::: "memory");
    SBAR();

    #pragma unroll 1
    for (int c = 0; c < NC; ++c) {
        mfmaC(c & 1);
        if (c + 2 < NC) {
            SBAR();
            stage(c + 2, c & 1);
            asm volatile("s_waitcnt vmcnt(5)" ::: "memory");
            SBAR();
        } else if (c + 1 < NC) {
            SBAR();
            asm volatile("s_waitcnt vmcnt(0)" ::: "memory");
            SBAR();
        }
    }

    const int nq4 = (lane >> 4) * 4;
    if (!F32OUT) {
        ushort* Y = (ushort*)Yg;
        #pragma unroll
        for (int f = 0; f < NF; ++f) {
            int n4 = n0 + wn0 + f * 16 + nq4;
            float bv0 = bias[BDIV3 ? n4 / 3 : n4];
            float bv1 = bias[BDIV3 ? (n4 + 1) / 3 : n4 + 1];
            float bv2 = bias[BDIV3 ? (n4 + 2) / 3 : n4 + 2];
            float bv3 = bias[BDIV3 ? (n4 + 3) / 3 : n4 + 3];
            #pragma unroll
            for (int mi = 0; mi < MF; ++mi) {
                int m = mbase + mi * 16 + ml;
                float x0 = acc[f][mi][0] + bv0, x1 = acc[f][mi][1] + bv1;
                float x2 = acc[f][mi][2] + bv2, x3 = acc[f][mi][3] + bv3;
                if (RELU) { x0 = fmaxf(x0, 0.f); x1 = fmaxf(x1, 0.f);
                            x2 = fmaxf(x2, 0.f); x3 = fmaxf(x3, 0.f); }
                ushort4 o = {f2bf(x0), f2bf(x1), f2bf(x2), f2bf(x3)};
                *(ushort4*)(Y + (size_t)(m0 + m) * ldy + n4) = o;
            }
        }
    } else {
        float* Y = (float*)Yg;
        #pragma unroll
        for (int f = 0; f < NF; ++f) {
            int nf = n0 + wn0 + f * 16;
            if (nf < 800) {
                int n4 = nf + nq4, sh = n4 & 31;
                float bv0 = bias[n4], bv1 = bias[n4 + 1];
                float bv2 = bias[n4 + 2], bv3 = bias[n4 + 3];
                #pragma unroll
                for (int mi = 0; mi < MF; ++mi) {
                    int m = mbase + mi * 16 + ml;
                    uint32_t mwv = maskg[(size_t)(m0 + m) * 25 + (nf >> 5)];
                    float4 v;
                    v.x = ((mwv >> (sh + 0)) & 1u) ? NEG_HUGE : (acc[f][mi][0] + bv0);
                    v.y = ((mwv >> (sh + 1)) & 1u) ? NEG_HUGE : (acc[f][mi][1] + bv1);
                    v.z = ((mwv >> (sh + 2)) & 1u) ? NEG_HUGE : (acc[f][mi][2] + bv2);
                    v.w = ((mwv >> (sh + 3)) & 1u) ? NEG_HUGE : (acc[f][mi][3] + bv3);
                    *(float4*)(Y + (size_t)(m0 + m) * ldy + n4) = v;
                }
            }
        }
    }
}

__global__ void ws_fail_kernel(float* out) {
    if (threadIdx.x == 0 && blockIdx.x == 0) out[0] = NAN;
}

extern "C" void kernel_launch(void* const* d_in, const int* in_sizes, int n_in,
                              void* d_out, int out_size, void* d_ws, size_t ws_size,
                              hipStream_t stream) {
    const float* state = (const float*)d_in[0];
    const float* w1  = (const float*)d_in[1];
    const float* b1  = (const float*)d_in[2];
    const float* w2  = (const float*)d_in[3];
    const float* b2  = (const float*)d_in[4];
    const float* w3  = (const float*)d_in[5];
    const float* b3  = (const float*)d_in[6];
    const float* wl1 = (const float*)d_in[7];
    const float* bl1 = (const float*)d_in[8];
    const float* wl2 = (const float*)d_in[9];
    const float* bl2 = (const float*)d_in[10];
    float* out = (float*)d_out;

    char* ws = (char*)d_ws;
    size_t off = 0;
    auto carve = [&](size_t bytes) {
        char* p = ws + off;
        off = (off + bytes + 255) & ~(size_t)255;
        return p;
    };
    ushort* W1T  = (ushort*)carve(384ull * 2432 * 2);
    ushort* W2T  = (ushort*)carve(768ull * 384 * 2);
    ushort* W3T  = (ushort*)carve(384ull * 768 * 2);
    ushort* WL1T = (ushort*)carve(192ull * 384 * 2);
    ushort* WL2T = (ushort*)carve(960ull * 192 * 2);
    ushort* X1g  = (ushort*)carve(16384ull * 384 * 2);
    ushort* X2g  = (ushort*)carve(16384ull * 768 * 2);
    ushort* X3g  = (ushort*)carve(16384ull * 384 * 2);
    ushort* X4g  = (ushort*)carve(16384ull * 192 * 2);
    uint32_t* maskg = (uint32_t*)carve(16384ull * 25 * 4);

    if (off > ws_size) {
        ws_fail_kernel<<<1, 64, 0, stream>>>(out);
        return;
    }

    prep_conv_T<<<(384 * 2432 + 255) / 256, 256, 0, stream>>>(w1, W1T, 800, 128, 384, 2432);
    prep_conv_T<<<(768 * 384 + 255) / 256, 256, 0, stream>>>(w2, W2T, 128, 256, 768, 384);
    prep_conv_T<<<(384 * 768 + 255) / 256, 256, 0, stream>>>(w3, W3T, 256, 128, 384, 768);
    prep_lin_T<<<(192 * 384 + 255) / 256, 256, 0, stream>>>(wl1, WL1T, 384, 192, 192);
    prep_lin_T<<<(960 * 192 + 255) / 256, 256, 0, stream>>>(wl2, WL2T, 192, 800, 960);

    // conv1 (fused convert+mask): state -> X1g, maskg; 2 blocks/CU
    (void)hipFuncSetAttribute(reinterpret_cast<const void*>(conv1_kernel),
                        hipFuncAttributeMaxDynamicSharedMemorySize, 71936);
    conv1_kernel<<<dim3(256, 2), 512, 71936, stream>>>(state, W1T, b1, X1g, maskg);

    // conv2: X1g[16384,384] @ W2T[768,384] -> X2g
    auto kc2 = glayer3<384, true, true, false>;
    (void)hipFuncSetAttribute(reinterpret_cast<const void*>(kc2),
                        hipFuncAttributeMaxDynamicSharedMemorySize, 81920);
    kc2<<<dim3(128, 4), 512, 81920, stream>>>(X1g, W2T, b2, X2g, 768, nullptr);

    // conv3: X2g[16384,768] @ W3T[384,768] -> X3g
    auto kc3 = glayer3<768, true, true, false>;
    (void)hipFuncSetAttribute(reinterpret_cast<const void*>(kc3),
                        hipFuncAttributeMaxDynamicSharedMemorySize, 81920);
    kc3<<<dim3(128, 2), 512, 81920, stream>>>(X2g, W3T, b3, X3g, 384, nullptr);

    // lin1: X3g[16384,384] @ WL1T[192,384] -> X4g
    auto kc4 = glayer3<384, false, true, false>;
    (void)hipFuncSetAttribute(reinterpret_cast<const void*>(kc4),
                        hipFuncAttributeMaxDynamicSharedMemorySize, 81920);
    kc4<<<dim3(128, 1), 512, 81920, stream>>>(X3g, WL1T, bl1, X4g, 192, nullptr);

    // lin2 + mask: X4g[16384,192] @ WL2T[960,192] -> out[16384,800] f32
    auto kc5 = glayer3<192, false, false, true>;
    (void)hipFuncSetAttribute(reinterpret_cast<const void*>(kc5),
                        hipFuncAttributeMaxDynamicSharedMemorySize, 81920);
    kc5<<<dim3(128, 5), 512, 81920, stream>>>(X4g, WL2T, bl2, out, 800, maskg);
}

// Round 16
// 132.424 us; speedup vs baseline: 1.2909x; 1.0652x over previous
//
#include <hip/hip_runtime.h>
#include <cstdint>
#include <cstddef>
#include <math.h>

typedef short bf16x8 __attribute__((ext_vector_type(8)));
typedef float f32x4 __attribute__((ext_vector_type(4)));
typedef unsigned long long u64;

#define NEG_HUGE (-3.0e38f)

__device__ __forceinline__ ushort f2bf(float x) {
    union { float f; uint32_t u; } a; a.f = x;
    uint32_t r = a.u + 0x7FFF + ((a.u >> 16) & 1);   // RNE
    return (ushort)(r >> 16);
}

__device__ __forceinline__ void gload_lds16(const void* g, void* l) {
    __builtin_amdgcn_global_load_lds(
        (const __attribute__((address_space(1))) uint32_t*)g,
        (__attribute__((address_space(3))) uint32_t*)l, 16, 0, 0);
}

#define SCHED() __builtin_amdgcn_sched_barrier(0)
#define SBAR() do { SCHED(); __builtin_amdgcn_s_barrier(); SCHED(); } while (0)

// ---------------- merged weight prep (single launch) ----------------
__device__ __forceinline__ ushort conv_elem(const float* __restrict__ w,
                                            int Cin, int idx, int Kpad) {
    int n = idx / Kpad, k = idx - n * Kpad;
    float val = 0.f;
    if (k < Cin * 3) {
        int co = n / 3, l = n % 3, ci = k / 3, lx = k % 3;
        int t = lx - l + 1;
        if (t >= 0 && t < 3) val = w[(co * Cin + ci) * 3 + t];
    }
    return f2bf(val);
}

__device__ __forceinline__ ushort lin_elem(const float* __restrict__ wl,
                                           int K, int Nreal, int idx) {
    int n = idx / K, k = idx - n * K;
    return (n < Nreal) ? f2bf(wl[n * K + k]) : (ushort)0;
}

// ranges: W1T 933888 | W2T 294912 | W3T 294912 | WL1T 73728 | WL2T 184320
__global__ void prep_all(const float* __restrict__ w1, const float* __restrict__ w2,
                         const float* __restrict__ w3, const float* __restrict__ wl1,
                         const float* __restrict__ wl2,
                         ushort* __restrict__ W1T, ushort* __restrict__ W2T,
                         ushort* __restrict__ W3T, ushort* __restrict__ WL1T,
                         ushort* __restrict__ WL2T) {
    int idx = blockIdx.x * 256 + threadIdx.x;
    if (idx < 933888) {
        W1T[idx] = conv_elem(w1, 800, idx, 2432);
        return;
    }
    idx -= 933888;
    if (idx < 294912) {
        W2T[idx] = conv_elem(w2, 128, idx, 384);
        return;
    }
    idx -= 294912;
    if (idx < 294912) {
        W3T[idx] = conv_elem(w3, 256, idx, 768);
        return;
    }
    idx -= 294912;
    if (idx < 73728) {
        WL1T[idx] = lin_elem(wl1, 384, 192, idx);
        return;
    }
    idx -= 73728;
    if (idx < 184320) {
        WL2T[idx] = lin_elem(wl2, 192, 800, idx);
    }
}

// ---------------- conv1: fused convert + mask + GEMM, 2 blocks/CU (R15, best) ----------------
// grid (256 m-tiles, 2 n-halves). Block: 64 rows x 192 cols, BK=64, 38 chunks.
// Queue algebra: at the wait, outstanding = W(c)3, S(c+1)2, W(c+1)3, S(c+2)2 = 10;
// vmcnt(7) drains exactly W(c). S(c+1) is drained by the compiler's register wait
// at stage_write(c+1) (2 chunk-times aged). Prologue issue order S(0) < W(0) < S(1).
__global__ __launch_bounds__(512, 4)
void conv1_kernel(const float* __restrict__ state, const ushort* __restrict__ W1T,
                  const float* __restrict__ b1, ushort* __restrict__ X1g,
                  uint32_t* __restrict__ maskg)
{
    extern __shared__ char lds[];
    char* BF0 = lds;                                // 64*128 = 8192
    char* BF1 = lds + 8192;
    char* Wb0 = lds + 16384;                        // 192*128 = 24576
    char* Wb1 = lds + 40960;
    uint32_t* maskw = (uint32_t*)(lds + 65536);     // [64][25] = 6400

    const int tid = threadIdx.x, lane = tid & 63, wid = tid >> 6;
    const int m0 = blockIdx.x * 64;
    const int n0 = blockIdx.y * 192;
    const bool domask = (blockIdx.y == 0);
    const int ml = lane & 15, kq = lane >> 4;
    const int mbase = (wid >> 2) * 32;              // 2 M-waves
    const int wn0 = (wid & 3) * 48;                 // 4 N-waves x 48 cols

    const int srow = tid >> 3, seg = tid & 7;       // 8 threads/row, 8 floats each
    const float* sbase = state + (size_t)(m0 + srow) * 2400 + seg * 8;

    f32x4 acc[3][2];
    #pragma unroll
    for (int f = 0; f < 3; ++f)
        #pragma unroll
        for (int mi = 0; mi < 2; ++mi) acc[f][mi] = (f32x4){0.f, 0.f, 0.f, 0.f};

    auto loadS = [&](float4 (&sv)[2], int c) {
        int kb = c * 64 + seg * 8;
        if (kb < 2400) {
            sv[0] = *(const float4*)(sbase + c * 64);
            sv[1] = *(const float4*)(sbase + c * 64 + 4);
        } else {
            sv[0] = (float4){0.f, 0.f, 0.f, 0.f};
            sv[1] = (float4){0.f, 0.f, 0.f, 0.f};
        }
    };
    auto stage_write = [&](float4 (&sv)[2], int c, char* dst) {
        float fv[8] = {sv[0].x, sv[0].y, sv[0].z, sv[0].w,
                       sv[1].x, sv[1].y, sv[1].z, sv[1].w};
        bf16x8 h;
        #pragma unroll
        for (int j = 0; j < 8; ++j) h[j] = (short)f2bf(fv[j]);
        *(bf16x8*)(dst + srow * 128 + ((seg * 16) ^ ((srow & 7) << 4))) = h;
        if (domask) {
            int kbase = c * 64 + seg * 8;
            int kmod = kbase % 3;
            uint32_t* mrow = &maskw[srow * 25];
            #define MCHK(J) { if (fv[J] != 0.0f) { int a = (kbase + (J)) / 3; \
                              atomicOr(&mrow[a >> 5], 1u << (a & 31)); } }
            if (kmod == 0)      { MCHK(2) MCHK(5) }
            else if (kmod == 1) { MCHK(1) MCHK(4) MCHK(7) }
            else                { MCHK(0) MCHK(3) MCHK(6) }
            #undef MCHK
        }
    };
    auto loadW = [&](int c, char* dst) {            // 24KB: rows n0..n0+191, k-chunk c
        #pragma unroll
        for (int i = 0; i < 3; ++i) {
            int s = i * 512 + tid;
            int r = s >> 3, o8 = s & 7;
            gload_lds16(W1T + (size_t)(n0 + r) * 2432 + c * 64 + ((o8 ^ (r & 7)) * 8),
                        dst + s * 16);
        }
    };
    auto mfmaC = [&](const char* wb, const char* sb) {
        #pragma unroll
        for (int ks = 0; ks < 2; ++ks) {
            bf16x8 af[3], bv[2];
            #pragma unroll
            for (int f = 0; f < 3; ++f) {
                int n = wn0 + f * 16 + ml;
                af[f] = *(const bf16x8*)(wb + n * 128 + (((ks * 4 + kq) * 16) ^ ((n & 7) << 4)));
            }
            #pragma unroll
            for (int mi = 0; mi < 2; ++mi) {
                int m = mbase + mi * 16 + ml;
                bv[mi] = *(const bf16x8*)(sb + m * 128 + (((ks * 4 + kq) * 16) ^ ((m & 7) << 4)));
            }
            #pragma unroll
            for (int f = 0; f < 3; ++f)
                #pragma unroll
                for (int mi = 0; mi < 2; ++mi)
                    acc[f][mi] = __builtin_amdgcn_mfma_f32_16x16x32_bf16(af[f], bv[mi], acc[f][mi], 0, 0, 0);
        }
    };

    for (int i = tid; i < 64 * 25; i += 512) maskw[i] = 0;
    float4 svA[2], svB[2];
    // prologue issue order MUST be S(0), W(0), S(1)
    loadS(svA, 0);
    loadW(0, Wb0);
    loadS(svB, 1);
    SCHED();
    asm volatile("s_waitcnt lgkmcnt(0)" ::: "memory");
    SBAR();    // mask zeros visible

    #define BODY(SV, C, SB, WBC, WBN) do {                                   \
        stage_write(SV, (C), SB);                                            \
        SCHED();                                                             \
        asm volatile("s_waitcnt lgkmcnt(0)" ::: "memory");                   \
        SBAR();                                                              \
        loadW(((C) + 1 > 37) ? 37 : (C) + 1, WBN);                           \
        loadS(SV, ((C) + 2 > 37) ? 37 : (C) + 2);                            \
        SCHED();                                                             \
        asm volatile("s_waitcnt vmcnt(7)" ::: "memory");                     \
        SBAR();                                                              \
        mfmaC(WBC, SB);                                                      \
    } while (0)

    #pragma unroll 1
    for (int p = 0; p < 19; ++p) {
        BODY(svA, 2 * p,     BF0, Wb0, Wb1);
        BODY(svB, 2 * p + 1, BF1, Wb1, Wb0);
    }
    #undef BODY

    asm volatile("s_waitcnt vmcnt(0) lgkmcnt(0)" ::: "memory");
    SBAR();

    // epilogue -> X1g [16384][384] bf16, cols n0..n0+191
    {
        const int nq4 = (lane >> 4) * 4;
        #pragma unroll
        for (int f = 0; f < 3; ++f) {
            int n4 = n0 + wn0 + f * 16 + nq4;
            float bv0 = b1[n4 / 3], bv1 = b1[(n4 + 1) / 3];
            float bv2 = b1[(n4 + 2) / 3], bv3 = b1[(n4 + 3) / 3];
            #pragma unroll
            for (int mi = 0; mi < 2; ++mi) {
                int m = mbase + mi * 16 + ml;
                ushort4 o;
                o.x = f2bf(fmaxf(acc[f][mi][0] + bv0, 0.f));
                o.y = f2bf(fmaxf(acc[f][mi][1] + bv1, 0.f));
                o.z = f2bf(fmaxf(acc[f][mi][2] + bv2, 0.f));
                o.w = f2bf(fmaxf(acc[f][mi][3] + bv3, 0.f));
                *(ushort4*)(X1g + (size_t)(m0 + m) * 384 + n4) = o;
            }
        }
    }

    // finalize combined mask (y==0 blocks only; one thread per sample)
    if (domask && tid < 64) {
        uint32_t* mw = &maskw[tid * 25];
        const u64 M40 = (1ull << 40) - 1;
        u64 ua = 0; uint32_t cf = 0;
        #pragma unroll
        for (int g = 0; g < 5; ++g) {
            uint32_t w0 = mw[5*g], w1 = mw[5*g+1], w2 = mw[5*g+2], w3 = mw[5*g+3], w4 = mw[5*g+4];
            u64 c0 = ( (u64)w0        | ((u64)w1 << 32)) & M40;
            u64 c1 = (((u64)w1 >> 8)  | ((u64)w2 << 24)) & M40;
            u64 c2 = (((u64)w2 >> 16) | ((u64)w3 << 16)) & M40;
            u64 c3 = (((u64)w3 >> 24) | ((u64)w4 << 8))  & M40;
            ua |= c0 | c1 | c2 | c3;
            if (__popcll(c0) >= 2) cf |= 1u << (4*g);
            if (__popcll(c1) >= 2) cf |= 1u << (4*g+1);
            if (__popcll(c2) >= 2) cf |= 1u << (4*g+2);
            if (__popcll(c3) >= 2) cf |= 1u << (4*g+3);
        }
        uint32_t* mg = maskg + (size_t)(m0 + tid) * 25;
        #pragma unroll
        for (int g = 0; g < 5; ++g) {
            uint32_t w0 = mw[5*g], w1 = mw[5*g+1], w2 = mw[5*g+2], w3 = mw[5*g+3], w4 = mw[5*g+4];
            u64 c0 = ( (u64)w0        | ((u64)w1 << 32)) & M40;
            u64 c1 = (((u64)w1 >> 8)  | ((u64)w2 << 24)) & M40;
            u64 c2 = (((u64)w2 >> 16) | ((u64)w3 << 16)) & M40;
            u64 c3 = (((u64)w3 >> 24) | ((u64)w4 << 8))  & M40;
            u64 m0v = c0 | ua | (((cf >> (4*g))     & 1u) ? M40 : 0ull);
            u64 m1v = c1 | ua | (((cf >> (4*g + 1)) & 1u) ? M40 : 0ull);
            u64 m2v = c2 | ua | (((cf >> (4*g + 2)) & 1u) ? M40 : 0ull);
            u64 m3v = c3 | ua | (((cf >> (4*g + 3)) & 1u) ? M40 : 0ull);
            mg[5*g]   = (uint32_t)m0v;
            mg[5*g+1] = (uint32_t)(m0v >> 32) | (uint32_t)(m1v << 8);
            mg[5*g+2] = (uint32_t)(m1v >> 24) | (uint32_t)(m2v << 16);
            mg[5*g+3] = (uint32_t)(m2v >> 16) | (uint32_t)(m3v << 24);
            mg[5*g+4] = (uint32_t)(m3v >> 8);
        }
    }
}

// ---------------- uniform GEMM layer, depth-2 counted pipeline (unchanged) ----------------
template<int K, bool BDIV3, bool RELU, bool F32OUT>
__global__ __launch_bounds__(512, 4)
void glayer3(const ushort* __restrict__ Ag, const ushort* __restrict__ WTg,
             const float* __restrict__ bias, void* __restrict__ Yg, int ldy,
             const uint32_t* __restrict__ maskg)
{
    constexpr int MF = 4, NF = 3;
    constexpr int MT = 128, NT = 192;
    constexpr int NC = K / 64;
    constexpr int ABYTES = MT * 128;
    constexpr int WBYTES = NT * 128;
    static_assert(NC >= 3, "pipeline assumes >=3 chunks");
    extern __shared__ char lds[];

    const int tid = threadIdx.x, lane = tid & 63, wid = tid >> 6;
    const int m0 = blockIdx.x * MT;
    const int n0 = blockIdx.y * NT;
    const int ml = lane & 15, kq = lane >> 4;
    const int mw = wid >> 2, nw = wid & 3;
    const int mbase = mw * MF * 16;
    const int wn0 = nw * NF * 16;

    f32x4 acc[NF][MF];
    #pragma unroll
    for (int f = 0; f < NF; ++f)
        #pragma unroll
        for (int mi = 0; mi < MF; ++mi) acc[f][mi] = (f32x4){0.f, 0.f, 0.f, 0.f};

    auto stage = [&](int c, int b) {
        char* Ab = lds + b * ABYTES;
        char* Wb = lds + 2 * ABYTES + b * WBYTES;
        #pragma unroll
        for (int i = 0; i < 2; ++i) {
            int s = i * 512 + tid;
            int r = s >> 3, o8 = s & 7;
            gload_lds16(Ag + (size_t)(m0 + r) * K + c * 64 + ((o8 ^ (r & 7)) * 8),
                        Ab + s * 16);
        }
        #pragma unroll
        for (int i = 0; i < 3; ++i) {
            int s = i * 512 + tid;
            int r = s >> 3, o8 = s & 7;
            gload_lds16(WTg + (size_t)(n0 + r) * K + c * 64 + ((o8 ^ (r & 7)) * 8),
                        Wb + s * 16);
        }
    };
    auto mfmaC = [&](int b) {
        const char* Ab = lds + b * ABYTES;
        const char* Wb = lds + 2 * ABYTES + b * WBYTES;
        #pragma unroll
        for (int ks = 0; ks < 2; ++ks) {
            bf16x8 af[NF], bv[MF];
            #pragma unroll
            for (int f = 0; f < NF; ++f) {
                int n = wn0 + f * 16 + ml;
                af[f] = *(const bf16x8*)(Wb + n * 128 + (((ks * 4 + kq) * 16) ^ ((n & 7) << 4)));
            }
            #pragma unroll
            for (int mi = 0; mi < MF; ++mi) {
                int m = mbase + mi * 16 + ml;
                bv[mi] = *(const bf16x8*)(Ab + m * 128 + (((ks * 4 + kq) * 16) ^ ((m & 7) << 4)));
            }
            #pragma unroll
            for (int f = 0; f < NF; ++f)
                #pragma unroll
                for (int mi = 0; mi < MF; ++mi)
                    acc[f][mi] = __builtin_amdgcn_mfma_f32_16x16x32_bf16(af[f], bv[mi], acc[f][mi], 0, 0, 0);
        }
    };

    stage(0, 0);
    stage(1, 1);
    asm volatile("s_waitcnt vmcnt(5)" ::: "memory");
    SBAR();

    #pragma unroll 1
    for (int c = 0; c < NC; ++c) {
        mfmaC(c & 1);
        if (c + 2 < NC) {
            SBAR();
            stage(c + 2, c & 1);
            asm volatile("s_waitcnt vmcnt(5)" ::: "memory");
            SBAR();
        } else if (c + 1 < NC) {
            SBAR();
            asm volatile("s_waitcnt vmcnt(0)" ::: "memory");
            SBAR();
        }
    }

    const int nq4 = (lane >> 4) * 4;
    if (!F32OUT) {
        ushort* Y = (ushort*)Yg;
        #pragma unroll
        for (int f = 0; f < NF; ++f) {
            int n4 = n0 + wn0 + f * 16 + nq4;
            float bv0 = bias[BDIV3 ? n4 / 3 : n4];
            float bv1 = bias[BDIV3 ? (n4 + 1) / 3 : n4 + 1];
            float bv2 = bias[BDIV3 ? (n4 + 2) / 3 : n4 + 2];
            float bv3 = bias[BDIV3 ? (n4 + 3) / 3 : n4 + 3];
            #pragma unroll
            for (int mi = 0; mi < MF; ++mi) {
                int m = mbase + mi * 16 + ml;
                float x0 = acc[f][mi][0] + bv0, x1 = acc[f][mi][1] + bv1;
                float x2 = acc[f][mi][2] + bv2, x3 = acc[f][mi][3] + bv3;
                if (RELU) { x0 = fmaxf(x0, 0.f); x1 = fmaxf(x1, 0.f);
                            x2 = fmaxf(x2, 0.f); x3 = fmaxf(x3, 0.f); }
                ushort4 o = {f2bf(x0), f2bf(x1), f2bf(x2), f2bf(x3)};
                *(ushort4*)(Y + (size_t)(m0 + m) * ldy + n4) = o;
            }
        }
    } else {
        float* Y = (float*)Yg;
        #pragma unroll
        for (int f = 0; f < NF; ++f) {
            int nf = n0 + wn0 + f * 16;
            if (nf < 800) {
                int n4 = nf + nq4, sh = n4 & 31;
                float bv0 = bias[n4], bv1 = bias[n4 + 1];
                float bv2 = bias[n4 + 2], bv3 = bias[n4 + 3];
                #pragma unroll
                for (int mi = 0; mi < MF; ++mi) {
                    int m = mbase + mi * 16 + ml;
                    uint32_t mwv = maskg[(size_t)(m0 + m) * 25 + (nf >> 5)];
                    float4 v;
                    v.x = ((mwv >> (sh + 0)) & 1u) ? NEG_HUGE : (acc[f][mi][0] + bv0);
                    v.y = ((mwv >> (sh + 1)) & 1u) ? NEG_HUGE : (acc[f][mi][1] + bv1);
                    v.z = ((mwv >> (sh + 2)) & 1u) ? NEG_HUGE : (acc[f][mi][2] + bv2);
                    v.w = ((mwv >> (sh + 3)) & 1u) ? NEG_HUGE : (acc[f][mi][3] + bv3);
                    *(float4*)(Y + (size_t)(m0 + m) * ldy + n4) = v;
                }
            }
        }
    }
}

__global__ void ws_fail_kernel(float* out) {
    if (threadIdx.x == 0 && blockIdx.x == 0) out[0] = NAN;
}

extern "C" void kernel_launch(void* const* d_in, const int* in_sizes, int n_in,
                              void* d_out, int out_size, void* d_ws, size_t ws_size,
                              hipStream_t stream) {
    const float* state = (const float*)d_in[0];
    const float* w1  = (const float*)d_in[1];
    const float* b1  = (const float*)d_in[2];
    const float* w2  = (const float*)d_in[3];
    const float* b2  = (const float*)d_in[4];
    const float* w3  = (const float*)d_in[5];
    const float* b3  = (const float*)d_in[6];
    const float* wl1 = (const float*)d_in[7];
    const float* bl1 = (const float*)d_in[8];
    const float* wl2 = (const float*)d_in[9];
    const float* bl2 = (const float*)d_in[10];
    float* out = (float*)d_out;

    char* ws = (char*)d_ws;
    size_t off = 0;
    auto carve = [&](size_t bytes) {
        char* p = ws + off;
        off = (off + bytes + 255) & ~(size_t)255;
        return p;
    };
    ushort* W1T  = (ushort*)carve(384ull * 2432 * 2);
    ushort* W2T  = (ushort*)carve(768ull * 384 * 2);
    ushort* W3T  = (ushort*)carve(384ull * 768 * 2);
    ushort* WL1T = (ushort*)carve(192ull * 384 * 2);
    ushort* WL2T = (ushort*)carve(960ull * 192 * 2);
    ushort* X1g  = (ushort*)carve(16384ull * 384 * 2);
    ushort* X2g  = (ushort*)carve(16384ull * 768 * 2);
    ushort* X3g  = (ushort*)carve(16384ull * 384 * 2);
    ushort* X4g  = (ushort*)carve(16384ull * 192 * 2);
    uint32_t* maskg = (uint32_t*)carve(16384ull * 25 * 4);

    if (off > ws_size) {
        ws_fail_kernel<<<1, 64, 0, stream>>>(out);
        return;
    }

    // merged weight prep: one launch for all five transforms (1,781,760 elems)
    prep_all<<<(1781760 + 255) / 256, 256, 0, stream>>>(w1, w2, w3, wl1, wl2,
                                                        W1T, W2T, W3T, WL1T, WL2T);

    // conv1 (fused convert+mask): state -> X1g, maskg; 2 blocks/CU
    (void)hipFuncSetAttribute(reinterpret_cast<const void*>(conv1_kernel),
                        hipFuncAttributeMaxDynamicSharedMemorySize, 71936);
    conv1_kernel<<<dim3(256, 2), 512, 71936, stream>>>(state, W1T, b1, X1g, maskg);

    // conv2: X1g[16384,384] @ W2T[768,384] -> X2g
    auto kc2 = glayer3<384, true, true, false>;
    (void)hipFuncSetAttribute(reinterpret_cast<const void*>(kc2),
                        hipFuncAttributeMaxDynamicSharedMemorySize, 81920);
    kc2<<<dim3(128, 4), 512, 81920, stream>>>(X1g, W2T, b2, X2g, 768, nullptr);

    // conv3: X2g[16384,768] @ W3T[384,768] -> X3g
    auto kc3 = glayer3<768, true, true, false>;
    (void)hipFuncSetAttribute(reinterpret_cast<const void*>(kc3),
                        hipFuncAttributeMaxDynamicSharedMemorySize, 81920);
    kc3<<<dim3(128, 2), 512, 81920, stream>>>(X2g, W3T, b3, X3g, 384, nullptr);

    // lin1: X3g[16384,384] @ WL1T[192,384] -> X4g
    auto kc4 = glayer3<384, false, true, false>;
    (void)hipFuncSetAttribute(reinterpret_cast<const void*>(kc4),
                        hipFuncAttributeMaxDynamicSharedMemorySize, 81920);
    kc4<<<dim3(128, 1), 512, 81920, stream>>>(X3g, WL1T, bl1, X4g, 192, nullptr);

    // lin2 + mask: X4g[16384,192] @ WL2T[960,192] -> out[16384,800] f32
    auto kc5 = glayer3<192, false, false, true>;
    (void)hipFuncSetAttribute(reinterpret_cast<const void*>(kc5),
                        hipFuncAttributeMaxDynamicSharedMemorySize, 81920);
    kc5<<<dim3(128, 5), 512, 81920, stream>>>(X4g, WL2T, bl2, out, 800, maskg);
}